// Round 18
// baseline (206.363 us; speedup 1.0000x reference)
//
#include <hip/hip_runtime.h>
#include <cstdint>

// Fused MQA block: q = x@Wq+bq (16 heads), k/v = x@Wk/Wv (+b) shared head,
// out = softmax(q k^T / sqrt(128)) v, then @Wo + bo.
// B=2, S=2048, DIM=2048, H=16, D=128. fp32 in/out, bf16 MFMA internally.
// Softmax scale C2 = log2(e)/sqrt(128) folded into Wq/bq at prep; attention
// computes p = exp2(score') fixed-shift (scores bounded; exact vs max-shift).
// Round 18: attention regridded to 32 q-rows/wave x 2048 one-wave blocks
// (round-6's PASSING grid: 8 blocks/CU = 2 waves/SIMD -> MFMA/VALU issue
// overlap across waves per m114) with the round-14/17 slim softmax body.
// No KV-split, no cross-wave combine (every variant of those failed).

#define SEQ 2048
#define NQKV 2304   // 2048 q + 128 k + 128 v
#define MTOT 4096   // B*S
#define C2SCALE 0.12752299126446508f  // (1/sqrt(128)) * log2(e)

typedef __attribute__((ext_vector_type(8))) short bf16x8;
typedef __attribute__((ext_vector_type(4))) float f32x4;
typedef __attribute__((ext_vector_type(16))) float f32x16;

__device__ __forceinline__ unsigned short cvt_bf16(float f) {
  union { float f; unsigned int u; } v; v.f = f;
  unsigned int r = v.u + 0x7FFFu + ((v.u >> 16) & 1u);  // RNE
  return (unsigned short)(r >> 16);
}

__device__ __forceinline__ unsigned cvt_pk_bf16(float lo, float hi_) {
  unsigned r;
  asm("v_cvt_pk_bf16_f32 %0, %1, %2" : "=v"(r) : "v"(lo), "v"(hi_));
  return r;
}

// a' = {a.lo32lanes, b.lo32lanes}; b' = {a.hi32lanes, b.hi32lanes}
__device__ __forceinline__ void plane_swap(unsigned &a, unsigned &b) {
  asm volatile("v_permlane32_swap_b32 %0, %1" : "+v"(a), "+v"(b));
}

__device__ __forceinline__ float exp2_(float x) {
#if __has_builtin(__builtin_amdgcn_exp2f)
  return __builtin_amdgcn_exp2f(x);
#else
  return exp2f(x);
#endif
}

typedef const __attribute__((address_space(1))) void gvoid;
typedef __attribute__((address_space(3))) void lvoid;
__device__ __forceinline__ void gload16(const void* g, void* l) {
  __builtin_amdgcn_global_load_lds((gvoid*)g, (lvoid*)l, 16, 0, 0);
}

// ---------------- fused prep kernel ----------------
// Block-range dispatch over 4 independent jobs:
//  [0,4096)      cast x (f32 -> bf16, 8 elem/thread)
//  [4096,8704)   W1T[n][k] = {Wq*C2 | Wk | Wv}[k][n'] transpose-cast (72x64 tiles)
//  [8704,12800)  WoT[n][k] = Wo[k][n] transpose-cast (64x64 tiles)
//  [12800,12809) bias concat (bq*C2 | bk | bv)
__global__ __launch_bounds__(256) void prep_kernel(
    const float* __restrict__ x,
    const float* __restrict__ Wq, const float* __restrict__ Wk,
    const float* __restrict__ Wv, const float* __restrict__ Wo,
    const float* __restrict__ bq, const float* __restrict__ bk,
    const float* __restrict__ bv,
    unsigned short* __restrict__ xb, unsigned short* __restrict__ W1T,
    unsigned short* __restrict__ WoT, float* __restrict__ b1) {
  __shared__ float t[32][33];
  const int bid = blockIdx.x, tid = threadIdx.x;
  if (bid < 4096) {
    long long i = ((long long)bid * 256 + tid) * 8;
    float4 a = *(const float4*)(x + i);
    float4 b = *(const float4*)(x + i + 4);
    union { bf16x8 v; unsigned short u[8]; } r;
    r.u[0] = cvt_bf16(a.x); r.u[1] = cvt_bf16(a.y); r.u[2] = cvt_bf16(a.z); r.u[3] = cvt_bf16(a.w);
    r.u[4] = cvt_bf16(b.x); r.u[5] = cvt_bf16(b.y); r.u[6] = cvt_bf16(b.z); r.u[7] = cvt_bf16(b.w);
    *(bf16x8*)(xb + i) = r.v;
    return;
  }
  if (bid < 12800) {
    // transpose-cast: dst[n][k] = src[k][n-off] * sc
    int n0, k0, off, stride;
    const float* src; float sc; unsigned short* dst;
    if (bid < 8704) {
      int idx = bid - 4096;
      n0 = (idx % 72) * 32; k0 = (idx / 72) * 32;
      if (n0 < 2048)      { src = Wq; off = 0;    stride = 2048; sc = C2SCALE; }
      else if (n0 < 2176) { src = Wk; off = 2048; stride = 128;  sc = 1.0f; }
      else                { src = Wv; off = 2176; stride = 128;  sc = 1.0f; }
      dst = W1T;
    } else {
      int idx = bid - 8704;
      n0 = (idx & 63) * 32; k0 = (idx >> 6) * 32;
      src = Wo; off = 0; stride = 2048; sc = 1.0f;
      dst = WoT;
    }
    int tx = tid & 31, ty = tid >> 5;
    #pragma unroll
    for (int r = 0; r < 4; r++)
      t[ty + r * 8][tx] = src[(size_t)(k0 + ty + r * 8) * stride + (n0 - off) + tx] * sc;
    __syncthreads();
    #pragma unroll
    for (int r = 0; r < 4; r++)
      dst[(size_t)(n0 + ty + r * 8) * 2048 + k0 + tx] = cvt_bf16(t[tx][ty + r * 8]);
    return;
  }
  int i = (bid - 12800) * 256 + tid;
  if (i < NQKV)
    b1[i] = (i < 2048) ? bq[i] * C2SCALE : (i < 2176 ? bk[i - 2048] : bv[i - 2176]);
}

// K fragments in exact 32x32x16 A-operand lane order:
// kfrag[((b*64+jt)*8+kt)*512 + l*8 + e] = K[b][jt*32 + (l&31)][kt*16 + (l>>5)*8 + e]
__global__ __launch_bounds__(256) void kfrag_prep(const unsigned short* __restrict__ qkv,
                                                  unsigned short* __restrict__ kfrag) {
  int gid = blockIdx.x * 4 + (threadIdx.x >> 6);  // 1024 groups
  int l = threadIdx.x & 63;
  int b = gid >> 9, rem = gid & 511;
  int jt = rem >> 3, kt = rem & 7;
  const unsigned short* src = qkv + (size_t)(b * 2048 + jt * 32 + (l & 31)) * NQKV
                              + 2048 + kt * 16 + (l >> 5) * 8;
  *(bf16x8*)(kfrag + (size_t)gid * 512 + l * 8) = *(const bf16x8*)src;
}

// V fragments in exact 32x32x16 B-operand lane order:
// vfrag[((b*64+jt)*8 + s*4+d0)*512 + l*8 + e]
//   = V[b][jt*32 + s*16 + (l>>5)*8 + e][d0*32 + (l&31)]
__global__ __launch_bounds__(256) void vfrag_prep(const unsigned short* __restrict__ qkv,
                                                  unsigned short* __restrict__ vfrag) {
  int gid = blockIdx.x * 4 + (threadIdx.x >> 6);  // 1024 groups
  int l = threadIdx.x & 63;
  int b = gid >> 9, rem = gid & 511;
  int jt = rem >> 3, s = (rem >> 2) & 1, d0 = rem & 3;
  union { bf16x8 v; unsigned short u[8]; } o;
  #pragma unroll
  for (int e = 0; e < 8; e++)
    o.u[e] = qkv[(size_t)(b * 2048 + jt * 32 + s * 16 + (l >> 5) * 8 + e) * NQKV
                 + 2176 + d0 * 32 + (l & 31)];
  *(bf16x8*)(vfrag + (size_t)gid * 512 + l * 8) = o.v;
}

// ---------------- GEMM (m97-style 128x128 tile, B^T input) ----------------
// C[M][N] = A[M][K=2048] * BT[N][K]^T + bias[N].  BF16_OUT: bf16 store, else f32.
template <int BF16_OUT>
__global__ __launch_bounds__(256) void gemm_bt(const unsigned short* __restrict__ A,
    const unsigned short* __restrict__ BT, const float* __restrict__ bias,
    void* __restrict__ Cout, int N) {
  __shared__ unsigned short As[128 * 32];
  __shared__ unsigned short Bs[128 * 32];
  const int tid = threadIdx.x;
  const int l = tid & 63, w = tid >> 6;
  const int l15 = l & 15, g = l >> 4;
  const int wr = w >> 1, wc = w & 1;
  const int brow = blockIdx.x * 128, bcol = blockIdx.y * 128;
  const int K = 2048;
  const unsigned short* ga = A + (size_t)(brow + w * 32 + (l >> 2)) * K + (l & 3) * 8;
  const unsigned short* gb = BT + (size_t)(bcol + w * 32 + (l >> 2)) * K + (l & 3) * 8;
  unsigned short* lA = &As[w * 1024];
  unsigned short* lB = &Bs[w * 1024];
  f32x4 acc[4][4];
  const f32x4 z = {0.f, 0.f, 0.f, 0.f};
  #pragma unroll
  for (int i = 0; i < 4; i++)
    #pragma unroll
    for (int j = 0; j < 4; j++) acc[i][j] = z;

  for (int kt = 0; kt < K; kt += 32) {
    gload16(ga + kt, lA);
    gload16(ga + kt + 16 * K, lA + 512);
    gload16(gb + kt, lB);
    gload16(gb + kt + 16 * K, lB + 512);
    __syncthreads();
    bf16x8 af[4], bfr[4];
    #pragma unroll
    for (int mi = 0; mi < 4; mi++)
      af[mi] = *(const bf16x8*)&As[(wr * 64 + mi * 16 + l15) * 32 + g * 8];
    #pragma unroll
    for (int ni = 0; ni < 4; ni++)
      bfr[ni] = *(const bf16x8*)&Bs[(wc * 64 + ni * 16 + l15) * 32 + g * 8];
    __syncthreads();
    #pragma unroll
    for (int mi = 0; mi < 4; mi++)
      #pragma unroll
      for (int ni = 0; ni < 4; ni++)
        acc[mi][ni] = __builtin_amdgcn_mfma_f32_16x16x32_bf16(af[mi], bfr[ni], acc[mi][ni], 0, 0, 0);
  }
  float* Cf = (float*)Cout;
  unsigned short* Cb = (unsigned short*)Cout;
  #pragma unroll
  for (int ni = 0; ni < 4; ni++) {
    int col = bcol + wc * 64 + ni * 16 + l15;
    float bv = bias[col];
    #pragma unroll
    for (int mi = 0; mi < 4; mi++) {
      int row = brow + wr * 64 + mi * 16 + g * 4;
      #pragma unroll
      for (int r = 0; r < 4; r++) {
        float v = acc[mi][ni][r] + bv;
        if (BF16_OUT) Cb[(size_t)(row + r) * N + col] = cvt_bf16(v);
        else          Cf[(size_t)(row + r) * N + col] = v;
      }
    }
  }
}

// ---------------- fused MQA attention (32 q-rows/wave, 2 waves/SIMD) ------
// 2048 blocks x 64 threads (1 wave); block = (b, h, 32-row q-tile) — the
// round-6 PASSING grid (8 blocks/CU = 2 waves/SIMD). Body = round-14/17
// slim softmax: frag-direct K/V, fixed-shift p=exp2(score'), tree-summed
// lsum, zero-C first MFMA, T12 cvt_pk+permlane repack.
__global__ __launch_bounds__(64, 2) void attn_kernel(
    const unsigned short* __restrict__ qkv, const unsigned short* __restrict__ kfrag,
    const unsigned short* __restrict__ vfrag, unsigned short* __restrict__ aout) {
  const int l = threadIdx.x, l31 = l & 31, hi = l >> 5;
  const int bid = blockIdx.x;
  const int qt = bid & 63, h = (bid >> 6) & 15, b = bid >> 10;

  // Q B-frags: qf[kt] = Q[i=l31][d = kt*16 + hi*8 + e]
  bf16x8 qf[8];
  {
    const unsigned short* qp =
        qkv + (size_t)(b * 2048 + qt * 32 + l31) * NQKV + h * 128 + hi * 8;
    #pragma unroll
    for (int kt = 0; kt < 8; kt++) qf[kt] = *(const bf16x8*)(qp + kt * 16);
  }
  const unsigned short* kp = kfrag + (size_t)b * 262144 + l * 8;
  const unsigned short* vp = vfrag + (size_t)b * 262144 + l * 8;

  f32x16 acc[4];
  #pragma unroll
  for (int d0 = 0; d0 < 4; d0++)
    #pragma unroll
    for (int r = 0; r < 16; r++) acc[d0][r] = 0.f;
  float lsum = 0.f;

  // read-only zero C-operand (16 VGPRs, initialized once)
  f32x16 zro;
  #pragma unroll
  for (int r = 0; r < 16; r++) zro[r] = 0.f;

  bf16x8 ka[8], kb2[8], va8[8], vb8[8];
  bf16x8 pa_v[2];     // P->A frags for tile t, consumed by PV(t) next half
  f32x16 se0, so0;    // QK accumulators (live QK -> softmax within a half)

#define LOADK(DST, T_) { _Pragma("unroll")                                     \
    for (int u = 0; u < 8; u++)                                                \
      DST[u] = *(const bf16x8*)(kp + (size_t)(T_) * 4096 + u * 512); }
#define LOADV(DST, T_) { _Pragma("unroll")                                     \
    for (int u = 0; u < 8; u++)                                                \
      DST[u] = *(const bf16x8*)(vp + (size_t)(T_) * 4096 + u * 512); }

// QK for tile: 2 independent accumulator chains; first MFMA consumes zro.
#define QK2(KC) {                                                              \
    se0 = __builtin_amdgcn_mfma_f32_32x32x16_bf16(KC[0], qf[0], zro, 0, 0, 0); \
    so0 = __builtin_amdgcn_mfma_f32_32x32x16_bf16(KC[1], qf[1], zro, 0, 0, 0); \
    _Pragma("unroll")                                                          \
    for (int kt = 1; kt < 4; kt++) {                                           \
      se0 = __builtin_amdgcn_mfma_f32_32x32x16_bf16(KC[2 * kt], qf[2 * kt], se0, 0, 0, 0); \
      so0 = __builtin_amdgcn_mfma_f32_32x32x16_bf16(KC[2 * kt + 1], qf[2 * kt + 1], so0, 0, 0, 0); \
    } }

// PV for tile t using pa_v computed by the previous half's softmax
#define PV2(VB) { _Pragma("unroll")                                            \
    for (int s = 0; s < 2; s++) {                                              \
      _Pragma("unroll")                                                        \
      for (int d0 = 0; d0 < 4; d0++)                                           \
        acc[d0] = __builtin_amdgcn_mfma_f32_32x32x16_bf16(pa_v[s], VB[s * 4 + d0], acc[d0], 0, 0, 0); \
    } }

// branchless softmax: p = exp2(score'), tree-summed lsum, repack -> pa_v
#define SM2() {                                                                \
    float p_[16];                                                              \
    _Pragma("unroll")                                                          \
    for (int r = 0; r < 16; r++) p_[r] = exp2_(se0[r] + so0[r]);               \
    float s01_ = p_[0] + p_[1],   s23_ = p_[2] + p_[3];                        \
    float s45_ = p_[4] + p_[5],   s67_ = p_[6] + p_[7];                        \
    float s89_ = p_[8] + p_[9],   sab_ = p_[10] + p_[11];                      \
    float scd_ = p_[12] + p_[13], sef_ = p_[14] + p_[15];                      \
    float q0_ = s01_ + s23_, q1_ = s45_ + s67_;                                \
    float q2_ = s89_ + sab_, q3_ = scd_ + sef_;                                \
    float rs_ = (q0_ + q1_) + (q2_ + q3_);                                     \
    rs_ += __shfl_xor(rs_, 32);                                                \
    lsum += rs_;                                                               \
    _Pragma("unroll")                                                          \
    for (int s = 0; s < 2; s++) {                                              \
      unsigned a0_ = cvt_pk_bf16(p_[s * 8 + 0], p_[s * 8 + 1]);                \
      unsigned b0_ = cvt_pk_bf16(p_[s * 8 + 4], p_[s * 8 + 5]);                \
      plane_swap(a0_, b0_);                                                    \
      unsigned a1_ = cvt_pk_bf16(p_[s * 8 + 2], p_[s * 8 + 3]);                \
      unsigned b1_ = cvt_pk_bf16(p_[s * 8 + 6], p_[s * 8 + 7]);                \
      plane_swap(a1_, b1_);                                                    \
      union { bf16x8 v; unsigned u[4]; } pa_;                                  \
      pa_.u[0] = a0_; pa_.u[1] = a1_; pa_.u[2] = b0_; pa_.u[3] = b1_;          \
      pa_v[s] = pa_.v;                                                         \
    } }

  // prologue: K/V for tiles 0,1; QK(0)+softmax(0) -> pa for PV(0)
  LOADK(ka, 0); LOADK(kb2, 1); LOADV(va8, 0); LOADV(vb8, 1);
  QK2(ka); SM2();

  for (int jt2 = 0; jt2 < 31; jt2++) {
    const int t0 = 2 * jt2;
    // half A (tile t0 even): QK(t0+1) || PV(t0); softmax(t0+1) under the pipe
    QK2(kb2); PV2(va8); LOADK(ka, t0 + 2); LOADV(va8, t0 + 2); SM2();
    // half B (tile t0+1 odd)
    QK2(ka); PV2(vb8); LOADK(kb2, t0 + 3); LOADV(vb8, t0 + 3); SM2();
  }
  // tile 62: QK(63) || PV(62); softmax(63)
  QK2(kb2); PV2(va8); SM2();
  // tile 63: PV only
  PV2(vb8);

#undef LOADK
#undef LOADV
#undef QK2
#undef PV2
#undef SM2

  // epilogue: O[i = crow(r,hi)][d = d0*32 + l31] / lsum[i]
  float linv = 1.0f / lsum;
  const int qrow0 = b * 2048 + qt * 32;
  #pragma unroll
  for (int r = 0; r < 16; r++) {
    const int crow = (r & 3) + 8 * (r >> 2) + 4 * hi;
    float li = __shfl(linv, crow);
    size_t rbase = (size_t)(qrow0 + crow) * 2048 + h * 128 + l31;
    #pragma unroll
    for (int d0 = 0; d0 < 4; d0++)
      aout[rbase + d0 * 32] = cvt_bf16(acc[d0][r] * li);
  }
}

// ---------------- launcher ----------------

extern "C" void kernel_launch(void* const* d_in, const int* in_sizes, int n_in,
                              void* d_out, int out_size, void* d_ws, size_t ws_size,
                              hipStream_t stream) {
  const float* x  = (const float*)d_in[0];
  const float* Wq = (const float*)d_in[1];
  const float* bq = (const float*)d_in[2];
  const float* Wk = (const float*)d_in[3];
  const float* bk = (const float*)d_in[4];
  const float* Wv = (const float*)d_in[5];
  const float* bv = (const float*)d_in[6];
  const float* Wo = (const float*)d_in[7];
  const float* bo = (const float*)d_in[8];
  float* out = (float*)d_out;

  char* ws = (char*)d_ws;
  size_t off = 0;
  auto alloc = [&](size_t bytes) -> void* {
    void* p = ws + off;
    off += (bytes + 255) & ~(size_t)255;
    return p;
  };
  unsigned short* xb     = (unsigned short*)alloc((size_t)MTOT * 2048 * 2);
  unsigned short* W1T    = (unsigned short*)alloc((size_t)NQKV * 2048 * 2);
  unsigned short* WoT    = (unsigned short*)alloc((size_t)2048 * 2048 * 2);
  float*          bias1  = (float*)alloc((size_t)NQKV * 4);
  unsigned short* qkv    = (unsigned short*)alloc((size_t)MTOT * NQKV * 2);
  unsigned short* kfragb = (unsigned short*)alloc((size_t)2 * 262144 * 2);
  unsigned short* vfragb = (unsigned short*)alloc((size_t)2 * 262144 * 2);
  unsigned short* aoutb  = (unsigned short*)alloc((size_t)MTOT * 2048 * 2);
  if (off > ws_size) return;  // workspace too small — fail loudly via validation

  prep_kernel<<<12809, 256, 0, stream>>>(x, Wq, Wk, Wv, Wo, bq, bk, bv,
                                         xb, W1T, WoT, bias1);
  gemm_bt<1><<<dim3(32, 18), 256, 0, stream>>>(xb, W1T, bias1, qkv, NQKV);
  kfrag_prep<<<256, 256, 0, stream>>>(qkv, kfragb);
  vfrag_prep<<<256, 256, 0, stream>>>(qkv, vfragb);
  attn_kernel<<<2048, 64, 0, stream>>>(qkv, kfragb, vfragb, aoutb);
  gemm_bt<0><<<dim3(32, 16), 256, 0, stream>>>(aoutb, WoT, bo, out, 2048);
}

// Round 19
// 192.979 us; speedup vs baseline: 1.0694x; 1.0694x over previous
//
#include <hip/hip_runtime.h>
#include <cstdint>

// Fused MQA block: q = x@Wq+bq (16 heads), k/v = x@Wk/Wv (+b) shared head,
// out = softmax(q k^T / sqrt(128)) v, then @Wo + bo.
// B=2, S=2048, DIM=2048, H=16, D=128. fp32 in/out, bf16 MFMA internally.
// Softmax scale C2 = log2(e)/sqrt(128) folded into Wq/bq at prep.
// Round 19: revert round-18's 32-row attn regrid (L2-BW wall: 20.7 TB/s,
// 101us vs 77us). Attn = round-17 passing version. New: merged frag-prep
// kernel (-1 launch) + bijective XCD swizzle on both GEMMs (T1: consecutive
// swizzled ids share B panels -> per-XCD L2 reuse; nwg 576/512 both %8==0).

#define SEQ 2048
#define NQKV 2304   // 2048 q + 128 k + 128 v
#define MTOT 4096   // B*S
#define C2SCALE 0.12752299126446508f  // (1/sqrt(128)) * log2(e)

typedef __attribute__((ext_vector_type(8))) short bf16x8;
typedef __attribute__((ext_vector_type(4))) float f32x4;
typedef __attribute__((ext_vector_type(16))) float f32x16;

__device__ __forceinline__ unsigned short cvt_bf16(float f) {
  union { float f; unsigned int u; } v; v.f = f;
  unsigned int r = v.u + 0x7FFFu + ((v.u >> 16) & 1u);  // RNE
  return (unsigned short)(r >> 16);
}

__device__ __forceinline__ unsigned cvt_pk_bf16(float lo, float hi_) {
  unsigned r;
  asm("v_cvt_pk_bf16_f32 %0, %1, %2" : "=v"(r) : "v"(lo), "v"(hi_));
  return r;
}

// a' = {a.lo32lanes, b.lo32lanes}; b' = {a.hi32lanes, b.hi32lanes}
__device__ __forceinline__ void plane_swap(unsigned &a, unsigned &b) {
  asm volatile("v_permlane32_swap_b32 %0, %1" : "+v"(a), "+v"(b));
}

__device__ __forceinline__ float exp2_(float x) {
#if __has_builtin(__builtin_amdgcn_exp2f)
  return __builtin_amdgcn_exp2f(x);
#else
  return exp2f(x);
#endif
}

typedef const __attribute__((address_space(1))) void gvoid;
typedef __attribute__((address_space(3))) void lvoid;
__device__ __forceinline__ void gload16(const void* g, void* l) {
  __builtin_amdgcn_global_load_lds((gvoid*)g, (lvoid*)l, 16, 0, 0);
}

// ---------------- fused prep kernel ----------------
// Block-range dispatch over 4 independent jobs:
//  [0,4096)      cast x (f32 -> bf16, 8 elem/thread)
//  [4096,8704)   W1T[n][k] = {Wq*C2 | Wk | Wv}[k][n'] transpose-cast (72x64 tiles)
//  [8704,12800)  WoT[n][k] = Wo[k][n] transpose-cast (64x64 tiles)
//  [12800,12809) bias concat (bq*C2 | bk | bv)
__global__ __launch_bounds__(256) void prep_kernel(
    const float* __restrict__ x,
    const float* __restrict__ Wq, const float* __restrict__ Wk,
    const float* __restrict__ Wv, const float* __restrict__ Wo,
    const float* __restrict__ bq, const float* __restrict__ bk,
    const float* __restrict__ bv,
    unsigned short* __restrict__ xb, unsigned short* __restrict__ W1T,
    unsigned short* __restrict__ WoT, float* __restrict__ b1) {
  __shared__ float t[32][33];
  const int bid = blockIdx.x, tid = threadIdx.x;
  if (bid < 4096) {
    long long i = ((long long)bid * 256 + tid) * 8;
    float4 a = *(const float4*)(x + i);
    float4 b = *(const float4*)(x + i + 4);
    union { bf16x8 v; unsigned short u[8]; } r;
    r.u[0] = cvt_bf16(a.x); r.u[1] = cvt_bf16(a.y); r.u[2] = cvt_bf16(a.z); r.u[3] = cvt_bf16(a.w);
    r.u[4] = cvt_bf16(b.x); r.u[5] = cvt_bf16(b.y); r.u[6] = cvt_bf16(b.z); r.u[7] = cvt_bf16(b.w);
    *(bf16x8*)(xb + i) = r.v;
    return;
  }
  if (bid < 12800) {
    // transpose-cast: dst[n][k] = src[k][n-off] * sc
    int n0, k0, off, stride;
    const float* src; float sc; unsigned short* dst;
    if (bid < 8704) {
      int idx = bid - 4096;
      n0 = (idx % 72) * 32; k0 = (idx / 72) * 32;
      if (n0 < 2048)      { src = Wq; off = 0;    stride = 2048; sc = C2SCALE; }
      else if (n0 < 2176) { src = Wk; off = 2048; stride = 128;  sc = 1.0f; }
      else                { src = Wv; off = 2176; stride = 128;  sc = 1.0f; }
      dst = W1T;
    } else {
      int idx = bid - 8704;
      n0 = (idx & 63) * 32; k0 = (idx >> 6) * 32;
      src = Wo; off = 0; stride = 2048; sc = 1.0f;
      dst = WoT;
    }
    int tx = tid & 31, ty = tid >> 5;
    #pragma unroll
    for (int r = 0; r < 4; r++)
      t[ty + r * 8][tx] = src[(size_t)(k0 + ty + r * 8) * stride + (n0 - off) + tx] * sc;
    __syncthreads();
    #pragma unroll
    for (int r = 0; r < 4; r++)
      dst[(size_t)(n0 + ty + r * 8) * 2048 + k0 + tx] = cvt_bf16(t[tx][ty + r * 8]);
    return;
  }
  int i = (bid - 12800) * 256 + tid;
  if (i < NQKV)
    b1[i] = (i < 2048) ? bq[i] * C2SCALE : (i < 2176 ? bk[i - 2048] : bv[i - 2176]);
}

// ---------------- merged K/V fragment prep ----------------
// blocks [0,256): kfrag[((b*64+jt)*8+kt)*512 + l*8 + e]
//                   = K[b][jt*32 + (l&31)][kt*16 + (l>>5)*8 + e]
// blocks [256,512): vfrag[((b*64+jt)*8 + s*4+d0)*512 + l*8 + e]
//                   = V[b][jt*32 + s*16 + (l>>5)*8 + e][d0*32 + (l&31)]
__global__ __launch_bounds__(256) void frag_prep(const unsigned short* __restrict__ qkv,
                                                 unsigned short* __restrict__ kfrag,
                                                 unsigned short* __restrict__ vfrag) {
  const int l = threadIdx.x & 63;
  if (blockIdx.x < 256) {
    int gid = blockIdx.x * 4 + (threadIdx.x >> 6);  // 1024 groups
    int b = gid >> 9, rem = gid & 511;
    int jt = rem >> 3, kt = rem & 7;
    const unsigned short* src = qkv + (size_t)(b * 2048 + jt * 32 + (l & 31)) * NQKV
                                + 2048 + kt * 16 + (l >> 5) * 8;
    *(bf16x8*)(kfrag + (size_t)gid * 512 + l * 8) = *(const bf16x8*)src;
  } else {
    int gid = (blockIdx.x - 256) * 4 + (threadIdx.x >> 6);
    int b = gid >> 9, rem = gid & 511;
    int jt = rem >> 3, s = (rem >> 2) & 1, d0 = rem & 3;
    union { bf16x8 v; unsigned short u[8]; } o;
    #pragma unroll
    for (int e = 0; e < 8; e++)
      o.u[e] = qkv[(size_t)(b * 2048 + jt * 32 + s * 16 + (l >> 5) * 8 + e) * NQKV
                   + 2176 + d0 * 32 + (l & 31)];
    *(bf16x8*)(vfrag + (size_t)gid * 512 + l * 8) = o.v;
  }
}

// ---------------- GEMM (m97-style 128x128 tile, B^T input, XCD-swizzled) --
// C[M][N] = A[M][K=2048] * BT[N][K]^T + bias[N].  BF16_OUT: bf16 store else f32.
// 1-D grid, nwg % 8 == 0. Bijective XCD swizzle: swz = (wg&7)*(nwg/8) + wg>>3;
// consecutive swz share by (B panel) -> per-XCD L2 panel reuse (T1).
template <int BF16_OUT>
__global__ __launch_bounds__(256) void gemm_bt(const unsigned short* __restrict__ A,
    const unsigned short* __restrict__ BT, const float* __restrict__ bias,
    void* __restrict__ Cout, int N) {
  __shared__ unsigned short As[128 * 32];
  __shared__ unsigned short Bs[128 * 32];
  const int tid = threadIdx.x;
  const int l = tid & 63, w = tid >> 6;
  const int l15 = l & 15, g = l >> 4;
  const int wr = w >> 1, wc = w & 1;
  const int nwg = gridDim.x, wg = blockIdx.x;
  const int swz = (wg & 7) * (nwg >> 3) + (wg >> 3);
  const int brow = (swz & 31) * 128, bcol = (swz >> 5) * 128;
  const int K = 2048;
  const unsigned short* ga = A + (size_t)(brow + w * 32 + (l >> 2)) * K + (l & 3) * 8;
  const unsigned short* gb = BT + (size_t)(bcol + w * 32 + (l >> 2)) * K + (l & 3) * 8;
  unsigned short* lA = &As[w * 1024];
  unsigned short* lB = &Bs[w * 1024];
  f32x4 acc[4][4];
  const f32x4 z = {0.f, 0.f, 0.f, 0.f};
  #pragma unroll
  for (int i = 0; i < 4; i++)
    #pragma unroll
    for (int j = 0; j < 4; j++) acc[i][j] = z;

  for (int kt = 0; kt < K; kt += 32) {
    gload16(ga + kt, lA);
    gload16(ga + kt + 16 * K, lA + 512);
    gload16(gb + kt, lB);
    gload16(gb + kt + 16 * K, lB + 512);
    __syncthreads();
    bf16x8 af[4], bfr[4];
    #pragma unroll
    for (int mi = 0; mi < 4; mi++)
      af[mi] = *(const bf16x8*)&As[(wr * 64 + mi * 16 + l15) * 32 + g * 8];
    #pragma unroll
    for (int ni = 0; ni < 4; ni++)
      bfr[ni] = *(const bf16x8*)&Bs[(wc * 64 + ni * 16 + l15) * 32 + g * 8];
    __syncthreads();
    #pragma unroll
    for (int mi = 0; mi < 4; mi++)
      #pragma unroll
      for (int ni = 0; ni < 4; ni++)
        acc[mi][ni] = __builtin_amdgcn_mfma_f32_16x16x32_bf16(af[mi], bfr[ni], acc[mi][ni], 0, 0, 0);
  }
  float* Cf = (float*)Cout;
  unsigned short* Cb = (unsigned short*)Cout;
  #pragma unroll
  for (int ni = 0; ni < 4; ni++) {
    int col = bcol + wc * 64 + ni * 16 + l15;
    float bv = bias[col];
    #pragma unroll
    for (int mi = 0; mi < 4; mi++) {
      int row = brow + wr * 64 + mi * 16 + g * 4;
      #pragma unroll
      for (int r = 0; r < 4; r++) {
        float v = acc[mi][ni][r] + bv;
        if (BF16_OUT) Cb[(size_t)(row + r) * N + col] = cvt_bf16(v);
        else          Cf[(size_t)(row + r) * N + col] = v;
      }
    }
  }
}

// ---------------- fused MQA attention (round-17 verbatim) ----------------
// 1024 blocks x 64 threads (1 wave), 64 q-rows/wave, K/V frag-direct from L2,
// fixed-shift softmax p = exp2(score') (scale folded into Wq/bq), tree-summed
// lsum, zero-C first MFMA. Passing structure — do not touch.
__global__ __launch_bounds__(64, 1) void attn_kernel(
    const unsigned short* __restrict__ qkv, const unsigned short* __restrict__ kfrag,
    const unsigned short* __restrict__ vfrag, unsigned short* __restrict__ aout) {
  const int l = threadIdx.x, l31 = l & 31, hi = l >> 5;
  const int bid = blockIdx.x;
  const int qt = bid & 31, h = (bid >> 5) & 15, b = bid >> 9;

  // Q B-frags for two 32-row q-blocks: qf[q2][kt] = Q[i=l31][d=kt*16+hi*8+e]
  bf16x8 qf[2][8];
  #pragma unroll
  for (int q2 = 0; q2 < 2; q2++) {
    const unsigned short* qp =
        qkv + (size_t)(b * 2048 + qt * 64 + q2 * 32 + l31) * NQKV + h * 128 + hi * 8;
    #pragma unroll
    for (int kt = 0; kt < 8; kt++) qf[q2][kt] = *(const bf16x8*)(qp + kt * 16);
  }
  const unsigned short* kp = kfrag + (size_t)b * 262144 + l * 8;
  const unsigned short* vp = vfrag + (size_t)b * 262144 + l * 8;

  f32x16 acc[2][4];
  #pragma unroll
  for (int q2 = 0; q2 < 2; q2++)
    #pragma unroll
    for (int d0 = 0; d0 < 4; d0++)
      #pragma unroll
      for (int r = 0; r < 16; r++) acc[q2][d0][r] = 0.f;
  float lsum[2] = {0.f, 0.f};

  // read-only zero C-operand (16 VGPRs, initialized once)
  f32x16 zro;
  #pragma unroll
  for (int r = 0; r < 16; r++) zro[r] = 0.f;

  bf16x8 ka[8], kb2[8], va8[8], vb8[8];
  bf16x8 pa_v[2][2];          // P->A frags for tile t, consumed by PV(t) next half
  f32x16 se0, so0, se1, so1;  // QK accumulators (live QK -> softmax within a half)

#define LOADK(DST, T_) { _Pragma("unroll")                                     \
    for (int u = 0; u < 8; u++)                                                \
      DST[u] = *(const bf16x8*)(kp + (size_t)(T_) * 4096 + u * 512); }
#define LOADV(DST, T_) { _Pragma("unroll")                                     \
    for (int u = 0; u < 8; u++)                                                \
      DST[u] = *(const bf16x8*)(vp + (size_t)(T_) * 4096 + u * 512); }

// QK for tile: 4 independent accumulator chains (2 per q-stream);
// first MFMA of each chain consumes the shared read-only zero vector.
#define QK2(KC) {                                                              \
    se0 = __builtin_amdgcn_mfma_f32_32x32x16_bf16(KC[0], qf[0][0], zro, 0, 0, 0); \
    so0 = __builtin_amdgcn_mfma_f32_32x32x16_bf16(KC[1], qf[0][1], zro, 0, 0, 0); \
    se1 = __builtin_amdgcn_mfma_f32_32x32x16_bf16(KC[0], qf[1][0], zro, 0, 0, 0); \
    so1 = __builtin_amdgcn_mfma_f32_32x32x16_bf16(KC[1], qf[1][1], zro, 0, 0, 0); \
    _Pragma("unroll")                                                          \
    for (int kt = 1; kt < 4; kt++) {                                           \
      se0 = __builtin_amdgcn_mfma_f32_32x32x16_bf16(KC[2 * kt], qf[0][2 * kt], se0, 0, 0, 0); \
      so0 = __builtin_amdgcn_mfma_f32_32x32x16_bf16(KC[2 * kt + 1], qf[0][2 * kt + 1], so0, 0, 0, 0); \
      se1 = __builtin_amdgcn_mfma_f32_32x32x16_bf16(KC[2 * kt], qf[1][2 * kt], se1, 0, 0, 0); \
      so1 = __builtin_amdgcn_mfma_f32_32x32x16_bf16(KC[2 * kt + 1], qf[1][2 * kt + 1], so1, 0, 0, 0); \
    } }

// PV for tile t using pa_v computed by the previous half's softmax
#define PV2(VB) { _Pragma("unroll")                                            \
    for (int s = 0; s < 2; s++) {                                              \
      _Pragma("unroll")                                                        \
      for (int d0 = 0; d0 < 4; d0++) {                                         \
        acc[0][d0] = __builtin_amdgcn_mfma_f32_32x32x16_bf16(pa_v[0][s], VB[s * 4 + d0], acc[0][d0], 0, 0, 0); \
        acc[1][d0] = __builtin_amdgcn_mfma_f32_32x32x16_bf16(pa_v[1][s], VB[s * 4 + d0], acc[1][d0], 0, 0, 0); \
      } } }

// branchless softmax: p = exp2(score'), tree-summed lsum, repack -> pa_v
#define SM1(SE, SO, Q2) {                                                      \
    float p_[16];                                                              \
    _Pragma("unroll")                                                          \
    for (int r = 0; r < 16; r++) p_[r] = exp2_(SE[r] + SO[r]);                 \
    float s01_ = p_[0] + p_[1],   s23_ = p_[2] + p_[3];                        \
    float s45_ = p_[4] + p_[5],   s67_ = p_[6] + p_[7];                        \
    float s89_ = p_[8] + p_[9],   sab_ = p_[10] + p_[11];                      \
    float scd_ = p_[12] + p_[13], sef_ = p_[14] + p_[15];                      \
    float q0_ = s01_ + s23_, q1_ = s45_ + s67_;                                \
    float q2_ = s89_ + sab_, q3_ = scd_ + sef_;                                \
    float rs_ = (q0_ + q1_) + (q2_ + q3_);                                     \
    rs_ += __shfl_xor(rs_, 32);                                                \
    lsum[Q2] += rs_;                                                           \
    _Pragma("unroll")                                                          \
    for (int s = 0; s < 2; s++) {                                              \
      unsigned a0_ = cvt_pk_bf16(p_[s * 8 + 0], p_[s * 8 + 1]);                \
      unsigned b0_ = cvt_pk_bf16(p_[s * 8 + 4], p_[s * 8 + 5]);                \
      plane_swap(a0_, b0_);                                                    \
      unsigned a1_ = cvt_pk_bf16(p_[s * 8 + 2], p_[s * 8 + 3]);                \
      unsigned b1_ = cvt_pk_bf16(p_[s * 8 + 6], p_[s * 8 + 7]);                \
      plane_swap(a1_, b1_);                                                    \
      union { bf16x8 v; unsigned u[4]; } pa_;                                  \
      pa_.u[0] = a0_; pa_.u[1] = a1_; pa_.u[2] = b0_; pa_.u[3] = b1_;          \
      pa_v[Q2][s] = pa_.v;                                                     \
    } }
#define SM2() { SM1(se0, so0, 0); SM1(se1, so1, 1); }

  // prologue: K/V for tiles 0,1; QK(0)+softmax(0) -> pa for PV(0)
  LOADK(ka, 0); LOADK(kb2, 1); LOADV(va8, 0); LOADV(vb8, 1);
  QK2(ka); SM2();

  for (int jt2 = 0; jt2 < 31; jt2++) {
    const int t0 = 2 * jt2;
    // half A (tile t0 even): QK(t0+1) || PV(t0); softmax(t0+1) under the pipe
    QK2(kb2); PV2(va8); LOADK(ka, t0 + 2); LOADV(va8, t0 + 2); SM2();
    // half B (tile t0+1 odd)
    QK2(ka); PV2(vb8); LOADK(kb2, t0 + 3); LOADV(vb8, t0 + 3); SM2();
  }
  // tile 62: QK(63) || PV(62); softmax(63)
  QK2(kb2); PV2(va8); SM2();
  // tile 63: PV only
  PV2(vb8);

#undef LOADK
#undef LOADV
#undef QK2
#undef PV2
#undef SM1
#undef SM2

  // epilogue: O[i = crow(r,hi)][d = d0*32 + l31] / lsum[i], per q-stream
  #pragma unroll
  for (int q2 = 0; q2 < 2; q2++) {
    float linv = 1.0f / lsum[q2];
    const int qrow0 = b * 2048 + qt * 64 + q2 * 32;
    #pragma unroll
    for (int r = 0; r < 16; r++) {
      const int crow = (r & 3) + 8 * (r >> 2) + 4 * hi;
      float li = __shfl(linv, crow);
      size_t rbase = (size_t)(qrow0 + crow) * 2048 + h * 128 + l31;
      #pragma unroll
      for (int d0 = 0; d0 < 4; d0++)
        aout[rbase + d0 * 32] = cvt_bf16(acc[q2][d0][r] * li);
    }
  }
}

// ---------------- launcher ----------------

extern "C" void kernel_launch(void* const* d_in, const int* in_sizes, int n_in,
                              void* d_out, int out_size, void* d_ws, size_t ws_size,
                              hipStream_t stream) {
  const float* x  = (const float*)d_in[0];
  const float* Wq = (const float*)d_in[1];
  const float* bq = (const float*)d_in[2];
  const float* Wk = (const float*)d_in[3];
  const float* bk = (const float*)d_in[4];
  const float* Wv = (const float*)d_in[5];
  const float* bv = (const float*)d_in[6];
  const float* Wo = (const float*)d_in[7];
  const float* bo = (const float*)d_in[8];
  float* out = (float*)d_out;

  char* ws = (char*)d_ws;
  size_t off = 0;
  auto alloc = [&](size_t bytes) -> void* {
    void* p = ws + off;
    off += (bytes + 255) & ~(size_t)255;
    return p;
  };
  unsigned short* xb     = (unsigned short*)alloc((size_t)MTOT * 2048 * 2);
  unsigned short* W1T    = (unsigned short*)alloc((size_t)NQKV * 2048 * 2);
  unsigned short* WoT    = (unsigned short*)alloc((size_t)2048 * 2048 * 2);
  float*          bias1  = (float*)alloc((size_t)NQKV * 4);
  unsigned short* qkv    = (unsigned short*)alloc((size_t)MTOT * NQKV * 2);
  unsigned short* kfragb = (unsigned short*)alloc((size_t)2 * 262144 * 2);
  unsigned short* vfragb = (unsigned short*)alloc((size_t)2 * 262144 * 2);
  unsigned short* aoutb  = (unsigned short*)alloc((size_t)MTOT * 2048 * 2);
  if (off > ws_size) return;  // workspace too small — fail loudly via validation

  prep_kernel<<<12809, 256, 0, stream>>>(x, Wq, Wk, Wv, Wo, bq, bk, bv,
                                         xb, W1T, WoT, bias1);
  gemm_bt<1><<<576, 256, 0, stream>>>(xb, W1T, bias1, qkv, NQKV);
  frag_prep<<<512, 256, 0, stream>>>(qkv, kfragb, vfragb);
  attn_kernel<<<1024, 64, 0, stream>>>(qkv, kfragb, vfragb, aoutb);
  gemm_bt<0><<<512, 256, 0, stream>>>(aoutb, WoT, bo, out, 2048);
}

// Round 20
// 186.802 us; speedup vs baseline: 1.1047x; 1.0331x over previous
//
#include <hip/hip_runtime.h>
#include <cstdint>

// Fused MQA block: q = x@Wq+bq (16 heads), k/v = x@Wk/Wv (+b) shared head,
// out = softmax(q k^T / sqrt(128)) v, then @Wo + bo.
// B=2, S=2048, DIM=2048, H=16, D=128. fp32 in/out, bf16 MFMA internally.
// Softmax scale C2 = log2(e)/sqrt(128) folded into Wq/bq at prep.
// Round 20 (final): round-17 configuration (best measured, 188.7us) with the
// merged frag_prep kernel kept. Round-19's XCD swizzle reverted: all GEMM
// operands are L3-resident, where T1 measures net-negative (m160), and the
// plain dim3 grid already gives consecutive blocks the same B panel.

#define SEQ 2048
#define NQKV 2304   // 2048 q + 128 k + 128 v
#define MTOT 4096   // B*S
#define C2SCALE 0.12752299126446508f  // (1/sqrt(128)) * log2(e)

typedef __attribute__((ext_vector_type(8))) short bf16x8;
typedef __attribute__((ext_vector_type(4))) float f32x4;
typedef __attribute__((ext_vector_type(16))) float f32x16;

__device__ __forceinline__ unsigned short cvt_bf16(float f) {
  union { float f; unsigned int u; } v; v.f = f;
  unsigned int r = v.u + 0x7FFFu + ((v.u >> 16) & 1u);  // RNE
  return (unsigned short)(r >> 16);
}

__device__ __forceinline__ unsigned cvt_pk_bf16(float lo, float hi_) {
  unsigned r;
  asm("v_cvt_pk_bf16_f32 %0, %1, %2" : "=v"(r) : "v"(lo), "v"(hi_));
  return r;
}

// a' = {a.lo32lanes, b.lo32lanes}; b' = {a.hi32lanes, b.hi32lanes}
__device__ __forceinline__ void plane_swap(unsigned &a, unsigned &b) {
  asm volatile("v_permlane32_swap_b32 %0, %1" : "+v"(a), "+v"(b));
}

__device__ __forceinline__ float exp2_(float x) {
#if __has_builtin(__builtin_amdgcn_exp2f)
  return __builtin_amdgcn_exp2f(x);
#else
  return exp2f(x);
#endif
}

typedef const __attribute__((address_space(1))) void gvoid;
typedef __attribute__((address_space(3))) void lvoid;
__device__ __forceinline__ void gload16(const void* g, void* l) {
  __builtin_amdgcn_global_load_lds((gvoid*)g, (lvoid*)l, 16, 0, 0);
}

// ---------------- fused prep kernel ----------------
// Block-range dispatch over 4 independent jobs:
//  [0,4096)      cast x (f32 -> bf16, 8 elem/thread)
//  [4096,8704)   W1T[n][k] = {Wq*C2 | Wk | Wv}[k][n'] transpose-cast (72x64 tiles)
//  [8704,12800)  WoT[n][k] = Wo[k][n] transpose-cast (64x64 tiles)
//  [12800,12809) bias concat (bq*C2 | bk | bv)
__global__ __launch_bounds__(256) void prep_kernel(
    const float* __restrict__ x,
    const float* __restrict__ Wq, const float* __restrict__ Wk,
    const float* __restrict__ Wv, const float* __restrict__ Wo,
    const float* __restrict__ bq, const float* __restrict__ bk,
    const float* __restrict__ bv,
    unsigned short* __restrict__ xb, unsigned short* __restrict__ W1T,
    unsigned short* __restrict__ WoT, float* __restrict__ b1) {
  __shared__ float t[32][33];
  const int bid = blockIdx.x, tid = threadIdx.x;
  if (bid < 4096) {
    long long i = ((long long)bid * 256 + tid) * 8;
    float4 a = *(const float4*)(x + i);
    float4 b = *(const float4*)(x + i + 4);
    union { bf16x8 v; unsigned short u[8]; } r;
    r.u[0] = cvt_bf16(a.x); r.u[1] = cvt_bf16(a.y); r.u[2] = cvt_bf16(a.z); r.u[3] = cvt_bf16(a.w);
    r.u[4] = cvt_bf16(b.x); r.u[5] = cvt_bf16(b.y); r.u[6] = cvt_bf16(b.z); r.u[7] = cvt_bf16(b.w);
    *(bf16x8*)(xb + i) = r.v;
    return;
  }
  if (bid < 12800) {
    // transpose-cast: dst[n][k] = src[k][n-off] * sc
    int n0, k0, off, stride;
    const float* src; float sc; unsigned short* dst;
    if (bid < 8704) {
      int idx = bid - 4096;
      n0 = (idx % 72) * 32; k0 = (idx / 72) * 32;
      if (n0 < 2048)      { src = Wq; off = 0;    stride = 2048; sc = C2SCALE; }
      else if (n0 < 2176) { src = Wk; off = 2048; stride = 128;  sc = 1.0f; }
      else                { src = Wv; off = 2176; stride = 128;  sc = 1.0f; }
      dst = W1T;
    } else {
      int idx = bid - 8704;
      n0 = (idx & 63) * 32; k0 = (idx >> 6) * 32;
      src = Wo; off = 0; stride = 2048; sc = 1.0f;
      dst = WoT;
    }
    int tx = tid & 31, ty = tid >> 5;
    #pragma unroll
    for (int r = 0; r < 4; r++)
      t[ty + r * 8][tx] = src[(size_t)(k0 + ty + r * 8) * stride + (n0 - off) + tx] * sc;
    __syncthreads();
    #pragma unroll
    for (int r = 0; r < 4; r++)
      dst[(size_t)(n0 + ty + r * 8) * 2048 + k0 + tx] = cvt_bf16(t[tx][ty + r * 8]);
    return;
  }
  int i = (bid - 12800) * 256 + tid;
  if (i < NQKV)
    b1[i] = (i < 2048) ? bq[i] * C2SCALE : (i < 2176 ? bk[i - 2048] : bv[i - 2176]);
}

// ---------------- merged K/V fragment prep ----------------
// blocks [0,256): kfrag[((b*64+jt)*8+kt)*512 + l*8 + e]
//                   = K[b][jt*32 + (l&31)][kt*16 + (l>>5)*8 + e]
// blocks [256,512): vfrag[((b*64+jt)*8 + s*4+d0)*512 + l*8 + e]
//                   = V[b][jt*32 + s*16 + (l>>5)*8 + e][d0*32 + (l&31)]
__global__ __launch_bounds__(256) void frag_prep(const unsigned short* __restrict__ qkv,
                                                 unsigned short* __restrict__ kfrag,
                                                 unsigned short* __restrict__ vfrag) {
  const int l = threadIdx.x & 63;
  if (blockIdx.x < 256) {
    int gid = blockIdx.x * 4 + (threadIdx.x >> 6);  // 1024 groups
    int b = gid >> 9, rem = gid & 511;
    int jt = rem >> 3, kt = rem & 7;
    const unsigned short* src = qkv + (size_t)(b * 2048 + jt * 32 + (l & 31)) * NQKV
                                + 2048 + kt * 16 + (l >> 5) * 8;
    *(bf16x8*)(kfrag + (size_t)gid * 512 + l * 8) = *(const bf16x8*)src;
  } else {
    int gid = (blockIdx.x - 256) * 4 + (threadIdx.x >> 6);
    int b = gid >> 9, rem = gid & 511;
    int jt = rem >> 3, s = (rem >> 2) & 1, d0 = rem & 3;
    union { bf16x8 v; unsigned short u[8]; } o;
    #pragma unroll
    for (int e = 0; e < 8; e++)
      o.u[e] = qkv[(size_t)(b * 2048 + jt * 32 + s * 16 + (l >> 5) * 8 + e) * NQKV
                   + 2176 + d0 * 32 + (l & 31)];
    *(bf16x8*)(vfrag + (size_t)gid * 512 + l * 8) = o.v;
  }
}

// ---------------- GEMM (m97-style 128x128 tile, B^T input) ----------------
// C[M][N] = A[M][K=2048] * BT[N][K]^T + bias[N].  BF16_OUT: bf16 store, else f32.
template <int BF16_OUT>
__global__ __launch_bounds__(256) void gemm_bt(const unsigned short* __restrict__ A,
    const unsigned short* __restrict__ BT, const float* __restrict__ bias,
    void* __restrict__ Cout, int N) {
  __shared__ unsigned short As[128 * 32];
  __shared__ unsigned short Bs[128 * 32];
  const int tid = threadIdx.x;
  const int l = tid & 63, w = tid >> 6;
  const int l15 = l & 15, g = l >> 4;
  const int wr = w >> 1, wc = w & 1;
  const int brow = blockIdx.x * 128, bcol = blockIdx.y * 128;
  const int K = 2048;
  const unsigned short* ga = A + (size_t)(brow + w * 32 + (l >> 2)) * K + (l & 3) * 8;
  const unsigned short* gb = BT + (size_t)(bcol + w * 32 + (l >> 2)) * K + (l & 3) * 8;
  unsigned short* lA = &As[w * 1024];
  unsigned short* lB = &Bs[w * 1024];
  f32x4 acc[4][4];
  const f32x4 z = {0.f, 0.f, 0.f, 0.f};
  #pragma unroll
  for (int i = 0; i < 4; i++)
    #pragma unroll
    for (int j = 0; j < 4; j++) acc[i][j] = z;

  for (int kt = 0; kt < K; kt += 32) {
    gload16(ga + kt, lA);
    gload16(ga + kt + 16 * K, lA + 512);
    gload16(gb + kt, lB);
    gload16(gb + kt + 16 * K, lB + 512);
    __syncthreads();
    bf16x8 af[4], bfr[4];
    #pragma unroll
    for (int mi = 0; mi < 4; mi++)
      af[mi] = *(const bf16x8*)&As[(wr * 64 + mi * 16 + l15) * 32 + g * 8];
    #pragma unroll
    for (int ni = 0; ni < 4; ni++)
      bfr[ni] = *(const bf16x8*)&Bs[(wc * 64 + ni * 16 + l15) * 32 + g * 8];
    __syncthreads();
    #pragma unroll
    for (int mi = 0; mi < 4; mi++)
      #pragma unroll
      for (int ni = 0; ni < 4; ni++)
        acc[mi][ni] = __builtin_amdgcn_mfma_f32_16x16x32_bf16(af[mi], bfr[ni], acc[mi][ni], 0, 0, 0);
  }
  float* Cf = (float*)Cout;
  unsigned short* Cb = (unsigned short*)Cout;
  #pragma unroll
  for (int ni = 0; ni < 4; ni++) {
    int col = bcol + wc * 64 + ni * 16 + l15;
    float bv = bias[col];
    #pragma unroll
    for (int mi = 0; mi < 4; mi++) {
      int row = brow + wr * 64 + mi * 16 + g * 4;
      #pragma unroll
      for (int r = 0; r < 4; r++) {
        float v = acc[mi][ni][r] + bv;
        if (BF16_OUT) Cb[(size_t)(row + r) * N + col] = cvt_bf16(v);
        else          Cf[(size_t)(row + r) * N + col] = v;
      }
    }
  }
}

// ---------------- fused MQA attention (round-17 verbatim) ----------------
// 1024 blocks x 64 threads (1 wave), 64 q-rows/wave, K/V frag-direct from L2,
// fixed-shift softmax p = exp2(score') (scale folded into Wq/bq), tree-summed
// lsum, zero-C first MFMA. Passing structure — do not touch.
__global__ __launch_bounds__(64, 1) void attn_kernel(
    const unsigned short* __restrict__ qkv, const unsigned short* __restrict__ kfrag,
    const unsigned short* __restrict__ vfrag, unsigned short* __restrict__ aout) {
  const int l = threadIdx.x, l31 = l & 31, hi = l >> 5;
  const int bid = blockIdx.x;
  const int qt = bid & 31, h = (bid >> 5) & 15, b = bid >> 9;

  // Q B-frags for two 32-row q-blocks: qf[q2][kt] = Q[i=l31][d=kt*16+hi*8+e]
  bf16x8 qf[2][8];
  #pragma unroll
  for (int q2 = 0; q2 < 2; q2++) {
    const unsigned short* qp =
        qkv + (size_t)(b * 2048 + qt * 64 + q2 * 32 + l31) * NQKV + h * 128 + hi * 8;
    #pragma unroll
    for (int kt = 0; kt < 8; kt++) qf[q2][kt] = *(const bf16x8*)(qp + kt * 16);
  }
  const unsigned short* kp = kfrag + (size_t)b * 262144 + l * 8;
  const unsigned short* vp = vfrag + (size_t)b * 262144 + l * 8;

  f32x16 acc[2][4];
  #pragma unroll
  for (int q2 = 0; q2 < 2; q2++)
    #pragma unroll
    for (int d0 = 0; d0 < 4; d0++)
      #pragma unroll
      for (int r = 0; r < 16; r++) acc[q2][d0][r] = 0.f;
  float lsum[2] = {0.f, 0.f};

  // read-only zero C-operand (16 VGPRs, initialized once)
  f32x16 zro;
  #pragma unroll
  for (int r = 0; r < 16; r++) zro[r] = 0.f;

  bf16x8 ka[8], kb2[8], va8[8], vb8[8];
  bf16x8 pa_v[2][2];          // P->A frags for tile t, consumed by PV(t) next half
  f32x16 se0, so0, se1, so1;  // QK accumulators (live QK -> softmax within a half)

#define LOADK(DST, T_) { _Pragma("unroll")                                     \
    for (int u = 0; u < 8; u++)                                                \
      DST[u] = *(const bf16x8*)(kp + (size_t)(T_) * 4096 + u * 512); }
#define LOADV(DST, T_) { _Pragma("unroll")                                     \
    for (int u = 0; u < 8; u++)                                                \
      DST[u] = *(const bf16x8*)(vp + (size_t)(T_) * 4096 + u * 512); }

// QK for tile: 4 independent accumulator chains (2 per q-stream);
// first MFMA of each chain consumes the shared read-only zero vector.
#define QK2(KC) {                                                              \
    se0 = __builtin_amdgcn_mfma_f32_32x32x16_bf16(KC[0], qf[0][0], zro, 0, 0, 0); \
    so0 = __builtin_amdgcn_mfma_f32_32x32x16_bf16(KC[1], qf[0][1], zro, 0, 0, 0); \
    se1 = __builtin_amdgcn_mfma_f32_32x32x16_bf16(KC[0], qf[1][0], zro, 0, 0, 0); \
    so1 = __builtin_amdgcn_mfma_f32_32x32x16_bf16(KC[1], qf[1][1], zro, 0, 0, 0); \
    _Pragma("unroll")                                                          \
    for (int kt = 1; kt < 4; kt++) {                                           \
      se0 = __builtin_amdgcn_mfma_f32_32x32x16_bf16(KC[2 * kt], qf[0][2 * kt], se0, 0, 0, 0); \
      so0 = __builtin_amdgcn_mfma_f32_32x32x16_bf16(KC[2 * kt + 1], qf[0][2 * kt + 1], so0, 0, 0, 0); \
      se1 = __builtin_amdgcn_mfma_f32_32x32x16_bf16(KC[2 * kt], qf[1][2 * kt], se1, 0, 0, 0); \
      so1 = __builtin_amdgcn_mfma_f32_32x32x16_bf16(KC[2 * kt + 1], qf[1][2 * kt + 1], so1, 0, 0, 0); \
    } }

// PV for tile t using pa_v computed by the previous half's softmax
#define PV2(VB) { _Pragma("unroll")                                            \
    for (int s = 0; s < 2; s++) {                                              \
      _Pragma("unroll")                                                        \
      for (int d0 = 0; d0 < 4; d0++) {                                         \
        acc[0][d0] = __builtin_amdgcn_mfma_f32_32x32x16_bf16(pa_v[0][s], VB[s * 4 + d0], acc[0][d0], 0, 0, 0); \
        acc[1][d0] = __builtin_amdgcn_mfma_f32_32x32x16_bf16(pa_v[1][s], VB[s * 4 + d0], acc[1][d0], 0, 0, 0); \
      } } }

// branchless softmax: p = exp2(score'), tree-summed lsum, repack -> pa_v
#define SM1(SE, SO, Q2) {                                                      \
    float p_[16];                                                              \
    _Pragma("unroll")                                                          \
    for (int r = 0; r < 16; r++) p_[r] = exp2_(SE[r] + SO[r]);                 \
    float s01_ = p_[0] + p_[1],   s23_ = p_[2] + p_[3];                        \
    float s45_ = p_[4] + p_[5],   s67_ = p_[6] + p_[7];                        \
    float s89_ = p_[8] + p_[9],   sab_ = p_[10] + p_[11];                      \
    float scd_ = p_[12] + p_[13], sef_ = p_[14] + p_[15];                      \
    float q0_ = s01_ + s23_, q1_ = s45_ + s67_;                                \
    float q2_ = s89_ + sab_, q3_ = scd_ + sef_;                                \
    float rs_ = (q0_ + q1_) + (q2_ + q3_);                                     \
    rs_ += __shfl_xor(rs_, 32);                                                \
    lsum[Q2] += rs_;                                                           \
    _Pragma("unroll")                                                          \
    for (int s = 0; s < 2; s++) {                                              \
      unsigned a0_ = cvt_pk_bf16(p_[s * 8 + 0], p_[s * 8 + 1]);                \
      unsigned b0_ = cvt_pk_bf16(p_[s * 8 + 4], p_[s * 8 + 5]);                \
      plane_swap(a0_, b0_);                                                    \
      unsigned a1_ = cvt_pk_bf16(p_[s * 8 + 2], p_[s * 8 + 3]);                \
      unsigned b1_ = cvt_pk_bf16(p_[s * 8 + 6], p_[s * 8 + 7]);                \
      plane_swap(a1_, b1_);                                                    \
      union { bf16x8 v; unsigned u[4]; } pa_;                                  \
      pa_.u[0] = a0_; pa_.u[1] = a1_; pa_.u[2] = b0_; pa_.u[3] = b1_;          \
      pa_v[Q2][s] = pa_.v;                                                     \
    } }
#define SM2() { SM1(se0, so0, 0); SM1(se1, so1, 1); }

  // prologue: K/V for tiles 0,1; QK(0)+softmax(0) -> pa for PV(0)
  LOADK(ka, 0); LOADK(kb2, 1); LOADV(va8, 0); LOADV(vb8, 1);
  QK2(ka); SM2();

  for (int jt2 = 0; jt2 < 31; jt2++) {
    const int t0 = 2 * jt2;
    // half A (tile t0 even): QK(t0+1) || PV(t0); softmax(t0+1) under the pipe
    QK2(kb2); PV2(va8); LOADK(ka, t0 + 2); LOADV(va8, t0 + 2); SM2();
    // half B (tile t0+1 odd)
    QK2(ka); PV2(vb8); LOADK(kb2, t0 + 3); LOADV(vb8, t0 + 3); SM2();
  }
  // tile 62: QK(63) || PV(62); softmax(63)
  QK2(kb2); PV2(va8); SM2();
  // tile 63: PV only
  PV2(vb8);

#undef LOADK
#undef LOADV
#undef QK2
#undef PV2
#undef SM1
#undef SM2

  // epilogue: O[i = crow(r,hi)][d = d0*32 + l31] / lsum[i], per q-stream
  #pragma unroll
  for (int q2 = 0; q2 < 2; q2++) {
    float linv = 1.0f / lsum[q2];
    const int qrow0 = b * 2048 + qt * 64 + q2 * 32;
    #pragma unroll
    for (int r = 0; r < 16; r++) {
      const int crow = (r & 3) + 8 * (r >> 2) + 4 * hi;
      float li = __shfl(linv, crow);
      size_t rbase = (size_t)(qrow0 + crow) * 2048 + h * 128 + l31;
      #pragma unroll
      for (int d0 = 0; d0 < 4; d0++)
        aout[rbase + d0 * 32] = cvt_bf16(acc[q2][d0][r] * li);
    }
  }
}

// ---------------- launcher ----------------

extern "C" void kernel_launch(void* const* d_in, const int* in_sizes, int n_in,
                              void* d_out, int out_size, void* d_ws, size_t ws_size,
                              hipStream_t stream) {
  const float* x  = (const float*)d_in[0];
  const float* Wq = (const float*)d_in[1];
  const float* bq = (const float*)d_in[2];
  const float* Wk = (const float*)d_in[3];
  const float* bk = (const float*)d_in[4];
  const float* Wv = (const float*)d_in[5];
  const float* bv = (const float*)d_in[6];
  const float* Wo = (const float*)d_in[7];
  const float* bo = (const float*)d_in[8];
  float* out = (float*)d_out;

  char* ws = (char*)d_ws;
  size_t off = 0;
  auto alloc = [&](size_t bytes) -> void* {
    void* p = ws + off;
    off += (bytes + 255) & ~(size_t)255;
    return p;
  };
  unsigned short* xb     = (unsigned short*)alloc((size_t)MTOT * 2048 * 2);
  unsigned short* W1T    = (unsigned short*)alloc((size_t)NQKV * 2048 * 2);
  unsigned short* WoT    = (unsigned short*)alloc((size_t)2048 * 2048 * 2);
  float*          bias1  = (float*)alloc((size_t)NQKV * 4);
  unsigned short* qkv    = (unsigned short*)alloc((size_t)MTOT * NQKV * 2);
  unsigned short* kfragb = (unsigned short*)alloc((size_t)2 * 262144 * 2);
  unsigned short* vfragb = (unsigned short*)alloc((size_t)2 * 262144 * 2);
  unsigned short* aoutb  = (unsigned short*)alloc((size_t)MTOT * 2048 * 2);
  if (off > ws_size) return;  // workspace too small — fail loudly via validation

  prep_kernel<<<12809, 256, 0, stream>>>(x, Wq, Wk, Wv, Wo, bq, bk, bv,
                                         xb, W1T, WoT, bias1);
  gemm_bt<1><<<dim3(32, 18), 256, 0, stream>>>(xb, W1T, bias1, qkv, NQKV);
  frag_prep<<<512, 256, 0, stream>>>(qkv, kfragb, vfragb);
  attn_kernel<<<1024, 64, 0, stream>>>(qkv, kfragb, vfragb, aoutb);
  gemm_bt<0><<<dim3(32, 16), 256, 0, stream>>>(aoutb, WoT, bo, out, 2048);
}